// Round 14
// baseline (18.179 us; speedup 1.0000x reference)
//
#include <hip/hip_runtime.h>

// Problem constants (match reference)
#define BATCH     16
#define SEQ_N     1024
#define EMBED_DIM 256
#define NTILE     16
#define STRIDEF   260   // padded row stride (floats): transpose read 2-way = free

typedef float f32x4 __attribute__((ext_vector_type(4)));

// out[b][d][n] = embedding[seq[b][n]][d]
//
// FINAL (R4 structure, 10.1us). Ledger of proven constraints:
//  - wave-uniform row loads: each wave-instr = one lane-linear 1KB embedding
//    row burst (diverged rows cost +6us: R6/R7)
//  - NT stores: cached stores cost +1.8us at any width (R5/R11, L2 thrash);
//    64B vs 128B NT chunks indistinguishable (R4 vs R9)
//  - >=4 barrier domains/CU with 512-thr blocks (R8: 1024-thr = +7us)
//  - global_load_lds regresses (+3.9us, vmcnt(0) barrier drain: R10)
//  - pipelining/double-buffer neutral (R12): not phase-chain-bound
//  - REPS probe (R13): marginal full-op pass = 2.0us (write-BW-saturated);
//    fixed ~8.1us is launch/dispatch overhead, structure-invariant
//    (R4/R9/R12 all 10.10 +- 0.03us).
__global__ __launch_bounds__(512) void
embed_gather_transpose(const int* __restrict__ seq,
                       const float* __restrict__ emb,
                       float* __restrict__ out) {
    __shared__ float buf[NTILE * STRIDEF];   // 16.6 KB

    const int tid = threadIdx.x;
    const int b   = blockIdx.x >> 6;          // 64 tiles per batch
    const int n0  = (blockIdx.x & 63) << 4;   // *NTILE
    const int* seqb = seq + b * SEQ_N + n0;
    float*     outb = out + ((size_t)b * EMBED_DIM) * SEQ_N + n0;

    // ---- load phase: 16 rows x 64 f32x4, wave-uniform 1KB row bursts ----
#pragma unroll
    for (int i = 0; i < 2; ++i) {
        const int flat = i * 512 + tid;
        const int nn   = flat >> 6;              // row in tile (wave-uniform)
        const int c4   = flat & 63;              // = lane
        const f32x4 v =
            reinterpret_cast<const f32x4*>(emb + (size_t)seqb[nn] * EMBED_DIM)[c4];
        *reinterpret_cast<f32x4*>(&buf[nn * STRIDEF + c4 * 4]) = v;
    }
    __syncthreads();

    // ---- store phase: 256 d x 4 f32x4, NT 64B line-aligned chunks ----
    // Transpose read bank = (16q + d) mod 32 -> 2 lanes/bank = free.
#pragma unroll
    for (int i = 0; i < 2; ++i) {
        const int flat = i * 512 + tid;
        const int d = flat >> 2, q = flat & 3, nn = q << 2;
        f32x4 v;
        v.x = buf[(nn + 0) * STRIDEF + d];
        v.y = buf[(nn + 1) * STRIDEF + d];
        v.z = buf[(nn + 2) * STRIDEF + d];
        v.w = buf[(nn + 3) * STRIDEF + d];
        __builtin_nontemporal_store(
            v, reinterpret_cast<f32x4*>(outb + (size_t)d * SEQ_N) + q);
    }
}

extern "C" void kernel_launch(void* const* d_in, const int* in_sizes, int n_in,
                              void* d_out, int out_size, void* d_ws, size_t ws_size,
                              hipStream_t stream) {
    const int*   seq = (const int*)d_in[0];
    const float* emb = (const float*)d_in[1];
    float*       out = (float*)d_out;

    const int grid = BATCH * (SEQ_N / NTILE);  // 16 * 64 = 1024 blocks
    embed_gather_transpose<<<grid, 512, 0, stream>>>(seq, emb, out);
}

// Round 15
// 10.076 us; speedup vs baseline: 1.8042x; 1.8042x over previous
//
#include <hip/hip_runtime.h>

// Problem constants (match reference)
#define BATCH       16
#define SEQ_N       1024
#define EMBED_DIM   256
#define NTILE       16     // n-values per block
#define LDS_STRIDE4 65     // float4 stride -> 260-float element stride (2-way read, free)

typedef float f32x4 __attribute__((ext_vector_type(4)));

// out[b][d][n] = embedding[seq[b][n]][d]
//
// BYTE-EXACT revert to the R4 kernel (measured 10.12us; same structure also
// 10.13 in R9 and 10.10 in R12). R14's 18.2us on equivalent code is treated
// as an environmental outlier — this round is a confirmation re-bench.
//
// Proven ledger:
//  - wave-uniform row loads (1KB lane-linear bursts); diverged rows +6us
//  - NT stores (cached +1.8us any width); 64B vs 128B NT chunks equal
//  - 512-thr blocks, 4 blocks/CU (1024-thr 2-domain structure +7us)
//  - global_load_lds +3.9us (vmcnt(0) barrier drain)
//  - double-buffer pipelining neutral; REPS probe: marginal pass 2.0us
//    (write-BW-saturated), fixed ~8.1us launch/replay overhead.
__global__ __launch_bounds__(512) void
embed_gather_transpose(const int* __restrict__ seq,
                       const float* __restrict__ emb,
                       float* __restrict__ out) {
    __shared__ f32x4 lds4[NTILE * LDS_STRIDE4];   // 16.6 KB
    const float* lds = reinterpret_cast<const float*>(lds4);

    const int b  = blockIdx.x >> 6;          // 64 tiles per batch
    const int n0 = (blockIdx.x & 63) << 4;   // *NTILE
    const int* seqb = seq + b * SEQ_N + n0;

    // ---- load phase: 16 rows x 64 float4 = 1024 float4, 2 per thread ----
    // nn = flat>>6 is wave-uniform; each wave-instr = one contiguous 1KB row.
#pragma unroll
    for (int i = 0; i < 2; ++i) {
        const int flat = i * 512 + threadIdx.x;  // 0..1023
        const int nn   = flat >> 6;              // row in tile (64 float4/row)
        const int c4   = flat & 63;              // float4 column
        const int row  = seqb[nn];               // 64B line, L1 broadcast
        lds4[nn * LDS_STRIDE4 + c4] =
            reinterpret_cast<const f32x4*>(emb + (size_t)row * EMBED_DIM)[c4];
    }
    __syncthreads();

    // ---- store phase: 256 d x 4 float4 (16 n) = 1024 float4, 2 per thread ----
    // 4 consecutive lanes emit one contiguous 64B chunk per d; 64B-aligned.
    // Transpose read: bank = (4*nn + d) mod 32 -> 2 lanes/bank = free.
    float* outb = out + ((size_t)b * EMBED_DIM) * SEQ_N + n0;
#pragma unroll
    for (int i = 0; i < 2; ++i) {
        const int flat = i * 512 + threadIdx.x;  // 0..1023
        const int d    = flat >> 2;
        const int q    = flat & 3;               // float4 index within 16-n chunk
        const int nn   = q << 2;
        f32x4 v;
        v.x = lds[(nn + 0) * (LDS_STRIDE4 * 4) + d];
        v.y = lds[(nn + 1) * (LDS_STRIDE4 * 4) + d];
        v.z = lds[(nn + 2) * (LDS_STRIDE4 * 4) + d];
        v.w = lds[(nn + 3) * (LDS_STRIDE4 * 4) + d];
        __builtin_nontemporal_store(
            v, reinterpret_cast<f32x4*>(outb + (size_t)d * SEQ_N) + q);
    }
}

extern "C" void kernel_launch(void* const* d_in, const int* in_sizes, int n_in,
                              void* d_out, int out_size, void* d_ws, size_t ws_size,
                              hipStream_t stream) {
    const int*   seq = (const int*)d_in[0];
    const float* emb = (const float*)d_in[1];
    float*       out = (float*)d_out;

    const int grid = BATCH * (SEQ_N / NTILE);  // 16 * 64 = 1024 blocks
    embed_gather_transpose<<<grid, 512, 0, stream>>>(seq, emb, out);
}